// Round 8
// baseline (103.081 us; speedup 1.0000x reference)
//
#include <hip/hip_runtime.h>
#include <math.h>

#define N 8192
#define FIN 256
#define FOUT 64
#define ALPHA 0.2f
#define LOG2E 1.442695040888963f

typedef float f32x4 __attribute__((ext_vector_type(4)));
typedef _Float16 f16x8 __attribute__((ext_vector_type(8)));

union F16V { uint4 u; int4 i; f16x8 h; };

__device__ __forceinline__ unsigned pack_f16(float a, float b) {
    union { _Float16 h; unsigned short u; } ca, cb;
    ca.h = (_Float16)a; cb.h = (_Float16)b;      // v_cvt_f16_f32, RNE
    return (unsigned)ca.u | ((unsigned)cb.u << 16);
}
// w' = exp(leaky(e)) * 2^-4  (scale cancels in softmax ratio; keeps f16 in range)
__device__ __forceinline__ float wcalc(int av, float fsr, float g) {
    float e = fsr + g;
    float le = e > 0.f ? e : ALPHA * e;
    float r = __builtin_exp2f(fmaf(le, LOG2E, -4.0f));
    return av != 0 ? r : 0.f;
}

// ---------------- Kernel 1: Wh = h@W -> fsrc/fdst + B_packed (pre-fragmented f16) ----
// Block = 512 thr / 32 rows (= one 32-col j-chunk of B_packed). Phase 2 writes
// B_packed[(chunk*4+ft)*64 + lane] = Wh[j0+(lane>>4)*8+e][ft*16+(lane&15)] so
// gat_main's B-fragment loads are single contiguous 16B/lane segments.
__global__ __launch_bounds__(512) void gat_prep(
    const float* __restrict__ h, const float* __restrict__ W,
    const float* __restrict__ a,
    float* __restrict__ fsrc, float* __restrict__ fdst,
    uint4* __restrict__ Bp)
{
    __shared__ float sWh[32][FOUT + 1];
    const int t = threadIdx.x;
    const int f = t & 63;
    const int wq = t >> 6;                 // 0..7, 4 rows each
    const int row0 = blockIdx.x * 32;
    const int rbase = row0 + wq * 4;

    float acc[4] = {0.f, 0.f, 0.f, 0.f};
    for (int k0 = 0; k0 < FIN; k0 += 4) {
        const float w0 = W[(k0 + 0) * FOUT + f];
        const float w1 = W[(k0 + 1) * FOUT + f];
        const float w2 = W[(k0 + 2) * FOUT + f];
        const float w3 = W[(k0 + 3) * FOUT + f];
#pragma unroll
        for (int rr = 0; rr < 4; ++rr) {
            const float4 hv = *reinterpret_cast<const float4*>(
                &h[(size_t)(rbase + rr) * FIN + k0]);
            acc[rr] = fmaf(hv.x, w0, acc[rr]);
            acc[rr] = fmaf(hv.y, w1, acc[rr]);
            acc[rr] = fmaf(hv.z, w2, acc[rr]);
            acc[rr] = fmaf(hv.w, w3, acc[rr]);
        }
    }
    const float as = a[f], ad = a[FOUT + f];
#pragma unroll
    for (int rr = 0; rr < 4; ++rr) {
        sWh[wq * 4 + rr][f] = acc[rr];
        float fs = acc[rr] * as, fd = acc[rr] * ad;
#pragma unroll
        for (int off = 1; off < 64; off <<= 1) {
            fs += __shfl_xor(fs, off, 64);
            fd += __shfl_xor(fd, off, 64);
        }
        if (f == 0) { fsrc[rbase + rr] = fs; fdst[rbase + rr] = fd; }
    }
    __syncthreads();
    if (t < 256) {
        const int ft = t >> 6;             // 0..3
        const int l = t & 63;
        const int li = l & 15, g = l >> 4;
        float v[8];
#pragma unroll
        for (int e = 0; e < 8; ++e) v[e] = sWh[g * 8 + e][ft * 16 + li];
        uint4 pk;
        pk.x = pack_f16(v[0], v[1]);
        pk.y = pack_f16(v[2], v[3]);
        pk.z = pack_f16(v[4], v[5]);
        pk.w = pack_f16(v[6], v[7]);
        Bp[(size_t)(blockIdx.x * 4 + ft) * 64 + l] = pk;
    }
}

// ---------------- Kernel 2: barrier-free streaming MFMA softmax-PV ----
// 8 waves/block, 16 shared rows; wave w owns j in [w*1024,(w+1)*1024), chunks
// of 32 cols. No LDS / no barriers in the main loop: A-frags computed in
// fragment layout from contiguous adj reads; B-frags are coalesced 16B/lane
// loads from B_packed. Depth-2 static register pipeline; waves drift freely.
struct Regs { int4 a0, a1; float4 g0, g1; uint4 b0, b1, b2, b3; };

__global__ __launch_bounds__(512, 4) void gat_main(
    const int* __restrict__ adj,
    const uint4* __restrict__ Bp,
    const float* __restrict__ fsrc, const float* __restrict__ fdst,
    float* __restrict__ out)
{
    __shared__ float accbuf[8][4][64][4];  // 32 KB
    __shared__ float zbuf[8][16];
    __shared__ float Zfin[16];

    const int t = threadIdx.x;
    const int l = t & 63;
    const int w = t >> 6;
    const int row0 = blockIdx.x * 16;
    const int r = l & 15;
    const int kg8 = (l >> 4) << 3;
    const int jwbase = w * 1024;
    const int cgbase = w * 32;
    const float fsr = fsrc[row0 + r];
    const size_t adjrow = (size_t)(row0 + r) * N;

    f32x4 acc0 = {0.f, 0.f, 0.f, 0.f};
    f32x4 acc1 = {0.f, 0.f, 0.f, 0.f};
    f32x4 acc2 = {0.f, 0.f, 0.f, 0.f};
    f32x4 acc3 = {0.f, 0.f, 0.f, 0.f};
    float zacc = 0.f;
    Regs RA, RB;

#define LOADG(cl, S)                                                           \
    {                                                                          \
        const int j0_ = jwbase + (cl) * 32;                                    \
        S.a0 = *reinterpret_cast<const int4*>(&adj[adjrow + j0_ + kg8]);       \
        S.a1 = *reinterpret_cast<const int4*>(&adj[adjrow + j0_ + kg8 + 4]);   \
        S.g0 = *reinterpret_cast<const float4*>(&fdst[j0_ + kg8]);             \
        S.g1 = *reinterpret_cast<const float4*>(&fdst[j0_ + kg8 + 4]);         \
        const uint4* bp_ = Bp + ((size_t)(cgbase + (cl)) * 4) * 64 + l;        \
        S.b0 = bp_[0];                                                         \
        S.b1 = bp_[64];                                                        \
        S.b2 = bp_[128];                                                       \
        S.b3 = bp_[192];                                                       \
    }

#define COMPUTE(S)                                                             \
    {                                                                          \
        const float w0 = wcalc(S.a0.x, fsr, S.g0.x);                           \
        const float w1 = wcalc(S.a0.y, fsr, S.g0.y);                           \
        const float w2 = wcalc(S.a0.z, fsr, S.g0.z);                           \
        const float w3 = wcalc(S.a0.w, fsr, S.g0.w);                           \
        const float w4 = wcalc(S.a1.x, fsr, S.g1.x);                           \
        const float w5 = wcalc(S.a1.y, fsr, S.g1.y);                           \
        const float w6 = wcalc(S.a1.z, fsr, S.g1.z);                           \
        const float w7 = wcalc(S.a1.w, fsr, S.g1.w);                           \
        zacc += (w0 + w1) + (w2 + w3) + ((w4 + w5) + (w6 + w7));               \
        F16V av, b0v, b1v, b2v, b3v;                                           \
        av.u.x = pack_f16(w0, w1); av.u.y = pack_f16(w2, w3);                  \
        av.u.z = pack_f16(w4, w5); av.u.w = pack_f16(w6, w7);                  \
        b0v.u = S.b0; b1v.u = S.b1; b2v.u = S.b2; b3v.u = S.b3;                \
        __builtin_amdgcn_s_setprio(1);                                         \
        acc0 = __builtin_amdgcn_mfma_f32_16x16x32_f16(av.h, b0v.h, acc0, 0, 0, 0); \
        acc1 = __builtin_amdgcn_mfma_f32_16x16x32_f16(av.h, b1v.h, acc1, 0, 0, 0); \
        acc2 = __builtin_amdgcn_mfma_f32_16x16x32_f16(av.h, b2v.h, acc2, 0, 0, 0); \
        acc3 = __builtin_amdgcn_mfma_f32_16x16x32_f16(av.h, b3v.h, acc3, 0, 0, 0); \
        __builtin_amdgcn_s_setprio(0);                                         \
    }

    LOADG(0, RA);
    LOADG(1, RB);
    for (int c = 0; c < 32; c += 2) {
        COMPUTE(RA);
        if (c + 2 < 32) LOADG(c + 2, RA);
        COMPUTE(RB);
        if (c + 3 < 32) LOADG(c + 3, RB);
    }
#undef LOADG
#undef COMPUTE

    // ---- cross-wave reduction (R3-verified epilogue) ----
    zacc += __shfl_xor(zacc, 16, 64);
    zacc += __shfl_xor(zacc, 32, 64);
    if (l < 16) zbuf[w][l] = zacc;
    *reinterpret_cast<f32x4*>(&accbuf[w][0][l][0]) = acc0;
    *reinterpret_cast<f32x4*>(&accbuf[w][1][l][0]) = acc1;
    *reinterpret_cast<f32x4*>(&accbuf[w][2][l][0]) = acc2;
    *reinterpret_cast<f32x4*>(&accbuf[w][3][l][0]) = acc3;
    __syncthreads();
    if (t < 16) {
        float z = 0.f;
#pragma unroll
        for (int w2 = 0; w2 < 8; ++w2) z += zbuf[w2][t];
        Zfin[t] = z;
    }
    __syncthreads();

    // D layout (verified): col = lane&15, row = (lane>>4)*4 + reg
#pragma unroll
    for (int e0 = 0; e0 < 2; ++e0) {
        const int e = t + e0 * 512;
        const int rr = e >> 6, f2 = e & 63;
        const int c = f2 >> 4;
        const int ln = (f2 & 15) | ((rr >> 2) << 4);
        const int rg = rr & 3;
        float s = 0.f;
#pragma unroll
        for (int w2 = 0; w2 < 8; ++w2) s += accbuf[w2][c][ln][rg];
        const float hp = s / Zfin[rr];
        out[(size_t)(row0 + rr) * FOUT + f2] = hp > 0.f ? hp : expm1f(hp);
    }
}

extern "C" void kernel_launch(void* const* d_in, const int* in_sizes, int n_in,
                              void* d_out, int out_size, void* d_ws, size_t ws_size,
                              hipStream_t stream) {
    const float* h   = (const float*)d_in[0];
    const int*   adj = (const int*)d_in[1];
    const float* W   = (const float*)d_in[2];
    const float* a   = (const float*)d_in[3];
    float* out = (float*)d_out;

    float* ws = (float*)d_ws;
    float* fsrc = ws;
    float* fdst = fsrc + N;
    uint4* Bp = (uint4*)(fdst + N);        // FOUT*N f16 = 1 MB, pre-fragmented

    gat_prep<<<dim3(N / 32), dim3(512), 0, stream>>>(h, W, a, fsrc, fdst, Bp);
    gat_main<<<dim3(N / 16), dim3(512), 0, stream>>>(adj, Bp, fsrc, fdst, out);
}